// Round 4
// baseline (798.317 us; speedup 1.0000x reference)
//
#include <hip/hip_runtime.h>
#include <cstdint>
#include <cstddef>

// ---------- types ----------
typedef __bf16 bf16;
typedef __bf16 bf16x8 __attribute__((ext_vector_type(8)));
typedef float  f32x4  __attribute__((ext_vector_type(4)));
typedef float  f32x16 __attribute__((ext_vector_type(16)));
typedef unsigned short u16x4v __attribute__((ext_vector_type(4)));
typedef unsigned int   u32x4v __attribute__((ext_vector_type(4)));

#define MFMA16(a, b, c) __builtin_amdgcn_mfma_f32_16x16x32_bf16((a), (b), (c), 0, 0, 0)
#define MFMA32(a, b, c) __builtin_amdgcn_mfma_f32_32x32x16_bf16((a), (b), (c), 0, 0, 0)

// async global->LDS, 16B per lane. LDS dst is wave-uniform base + lane*16 (HW adds lane part).
__device__ __forceinline__ void glds16(const bf16* g, bf16* l) {
    __builtin_amdgcn_global_load_lds(
        (__attribute__((address_space(1))) void*)(g),
        (__attribute__((address_space(3))) void*)(l), 16, 0, 0);
}

// pack two f32 -> one u32 of 2x bf16 (no builtin on gfx950; guide T12)
__device__ __forceinline__ unsigned cvtpk_bf16(float lo, float hi) {
    unsigned r;
    asm("v_cvt_pk_bf16_f32 %0, %1, %2" : "=v"(r) : "v"(lo), "v"(hi));
    return r;
}

// ---------- conversion kernels ----------
// generic f32 -> bf16 (used for Wo mid-pipeline)
__global__ __launch_bounds__(256) void cvt_bf16_k(const float* __restrict__ in,
                                                  bf16* __restrict__ out, long long n) {
    long long i = ((long long)blockIdx.x * 256 + threadIdx.x) * 8;
    if (i >= n) return;
    const float4* p = (const float4*)(in + i);
    float4 a = p[0], b = p[1];
    bf16x8 o;
    o[0] = (bf16)a.x; o[1] = (bf16)a.y; o[2] = (bf16)a.z; o[3] = (bf16)a.w;
    o[4] = (bf16)b.x; o[5] = (bf16)b.y; o[6] = (bf16)b.z; o[7] = (bf16)b.w;
    *(bf16x8*)(out + i) = o;
}

// fused: hidden -> Xb | Wq -> Wqb | Wk -> Wkvb[0:1024) | Wv -> Wkvb[1024:2048) | past_k -> Kb rows 0..1023
__global__ __launch_bounds__(256) void fused_cvt_k(const float* __restrict__ hidden,
                                                   const float* __restrict__ Wq,
                                                   const float* __restrict__ Wk,
                                                   const float* __restrict__ Wv,
                                                   const float* __restrict__ past_k,
                                                   bf16* __restrict__ Xb,
                                                   bf16* __restrict__ Wqb,
                                                   bf16* __restrict__ Wkvb,
                                                   bf16* __restrict__ Kb) {
    long long e = ((long long)blockIdx.x * 256 + threadIdx.x) * 8;
    const float* src;
    bf16* dst;
    if (e < 16777216ll) {
        src = hidden + e;           dst = Xb + e;
    } else if (e < 33554432ll) {
        long long i = e - 16777216ll;
        src = Wq + i;               dst = Wqb + i;
    } else if (e < 37748736ll) {
        long long i = e - 33554432ll;
        src = Wk + i;               dst = Wkvb + i;
    } else if (e < 41943040ll) {
        long long i = e - 37748736ll;
        src = Wv + i;               dst = Wkvb + 4194304ll + i;
    } else {
        long long i = e - 41943040ll;
        src = past_k + i;
        dst = Kb + (i >> 17) * 262144ll + (i & 131071ll);
    }
    const float4* p = (const float4*)src;
    float4 a = p[0], b = p[1];
    bf16x8 o;
    o[0] = (bf16)a.x; o[1] = (bf16)a.y; o[2] = (bf16)a.z; o[3] = (bf16)a.w;
    o[4] = (bf16)b.x; o[5] = (bf16)b.y; o[6] = (bf16)b.z; o[7] = (bf16)b.w;
    *(bf16x8*)dst = o;
}

// past_v [4][8][1024][128] f32 -> Vt [4][8][128][2048] bf16, LDS-transposed.
// grid 512 = [bh 32][kb 16]; coalesced float4 reads, 64B-contiguous writes per lane.
__global__ __launch_bounds__(256) void cvt_pastv_k(const float* __restrict__ in,
                                                   bf16* __restrict__ Vt) {
    __shared__ bf16 T[128][72];    // [d][kv], pad to 72 elems (144B rows)
    const int t = threadIdx.x;
    const int bh = blockIdx.x >> 4, kb = blockIdx.x & 15;
    const int r  = t >> 2;               // kv row 0..63
    const int c0 = (t & 3) * 32;         // d col base
    const float* src = in + ((long long)bh * 1024 + kb * 64 + r) * 128 + c0;
#pragma unroll
    for (int i = 0; i < 8; ++i) {
        float4 f = *(const float4*)(src + i * 4);
        T[c0 + i * 4 + 0][r] = (bf16)f.x;
        T[c0 + i * 4 + 1][r] = (bf16)f.y;
        T[c0 + i * 4 + 2][r] = (bf16)f.z;
        T[c0 + i * 4 + 3][r] = (bf16)f.w;
    }
    __syncthreads();
    const int d = t >> 1, ho = (t & 1) * 32;
    bf16* dst = Vt + ((long long)bh * 128 + d) * 2048 + kb * 64 + ho;
#pragma unroll
    for (int j = 0; j < 8; ++j) {
        u16x4v pk;
#pragma unroll
        for (int q = 0; q < 4; ++q)
            pk[q] = __builtin_bit_cast(unsigned short, T[d][ho + j * 4 + q]);
        *(u16x4v*)(dst + j * 4) = pk;
    }
}

// ---------- fused K+V projection, 128x128 tile, N=2048 ----------
__global__ __launch_bounds__(256) void gemm_kv(const bf16* __restrict__ A,
                                               const bf16* __restrict__ B,
                                               const float* __restrict__ bk,
                                               const float* __restrict__ bv,
                                               bf16* __restrict__ Kc,
                                               bf16* __restrict__ Vt,
                                               int K) {
    __shared__ bf16 Asm[128 * 32];
    __shared__ bf16 Bsm[128 * 32];
    const int t = threadIdx.x;
    const int lane = t & 63, w = t >> 6;
    const int quad = lane >> 4, l16 = lane & 15;
    const int wr = (w >> 1) * 64, wc = (w & 1) * 64;
    const long long m0 = (long long)blockIdx.y * 128, n0 = (long long)blockIdx.x * 128;

    f32x4 acc[4][4] = {};

    const int i1 = t, i2 = t + 256;
    const bf16* gA1 = A + (m0 + (i1 >> 2)) * K + (i1 & 3) * 8;
    const bf16* gA2 = A + (m0 + (i2 >> 2)) * K + (i2 & 3) * 8;
    const bf16* gB1 = B + (n0 + (i1 >> 2)) * K + (i1 & 3) * 8;
    const bf16* gB2 = B + (n0 + (i2 >> 2)) * K + (i2 & 3) * 8;
    bf16* lA1 = Asm + i1 * 8;
    bf16* lA2 = Asm + i2 * 8;
    bf16* lB1 = Bsm + i1 * 8;
    bf16* lB2 = Bsm + i2 * 8;

    for (int k0 = 0; k0 < K; k0 += 32) {
        glds16(gA1 + k0, lA1);
        glds16(gA2 + k0, lA2);
        glds16(gB1 + k0, lB1);
        glds16(gB2 + k0, lB2);
        __syncthreads();
        bf16x8 af[4], bfr[4];
#pragma unroll
        for (int i = 0; i < 4; ++i)
            af[i] = *(const bf16x8*)(Asm + (wr + i * 16 + l16) * 32 + quad * 8);
#pragma unroll
        for (int j = 0; j < 4; ++j)
            bfr[j] = *(const bf16x8*)(Bsm + (wc + j * 16 + l16) * 32 + quad * 8);
#pragma unroll
        for (int i = 0; i < 4; ++i)
#pragma unroll
            for (int j = 0; j < 4; ++j)
                acc[i][j] = MFMA16(af[i], bfr[j], acc[i][j]);
        __syncthreads();
    }

    const bool isK = (n0 < 1024);
    const long long c0 = isK ? n0 : (n0 - 1024);
    const float* bias = isK ? (bk + c0) : (bv + c0);

    float bs[4];
#pragma unroll
    for (int j = 0; j < 4; ++j) bs[j] = bias[wc + j * 16 + l16];

#pragma unroll
    for (int i = 0; i < 4; ++i) {
        const long long mbase = m0 + wr + i * 16 + quad * 4;
#pragma unroll
        for (int j = 0; j < 4; ++j) {
            const long long col = c0 + wc + j * 16 + l16;
            const int h = (int)(col >> 7), d = (int)(col & 127);
            if (isK) {
#pragma unroll
                for (int r = 0; r < 4; ++r) {
                    const long long m = mbase + r;
                    const long long bb = m >> 10, s = m & 1023;
                    Kc[((bb * 8 + h) * 2048 + 1024 + s) * 128 + d] = (bf16)(acc[i][j][r] + bs[j]);
                }
            } else {
                const long long bb = mbase >> 10, s = mbase & 1023;
                u16x4v pk;
#pragma unroll
                for (int r = 0; r < 4; ++r)
                    pk[r] = __builtin_bit_cast(unsigned short, (bf16)(acc[i][j][r] + bs[j]));
                *(u16x4v*)(Vt + ((bb * 8 + h) * 128 + d) * 2048 + 1024 + s) = pk;
            }
        }
    }
}

// ---------- 256x256-tile deep-pipelined GEMM (big projections) ----------
template <int MODE>
__global__ __launch_bounds__(512, 2) void gemm256(const bf16* __restrict__ A,
                                                  const bf16* __restrict__ B,
                                                  const float* __restrict__ bias,
                                                  void* __restrict__ Cv,
                                                  int M, int N, int K, float scale) {
    __shared__ bf16 S[4][16384];   // 4 buffers x (A 8192 + B 8192) elems = 128 KiB
    const int t = threadIdx.x, lane = t & 63, w = t >> 6;
    const int quad = lane >> 4, l16 = lane & 15;
    const int wm = w >> 2, wn = w & 3;

    const int nwg = gridDim.x * gridDim.y;
    const int bid = blockIdx.y * gridDim.x + blockIdx.x;
    const int lid = (bid & 7) * (nwg >> 3) + (bid >> 3);
    const long long m0 = (long long)(lid / gridDim.x) * 256;
    const long long n0 = (long long)(lid % gridDim.x) * 256;

    const int sA   = (lane & 7) ^ (lane >> 3);
    const int rsub = 2 * (lane >> 3) + (sA >> 2);
    const int colk = (sA & 3) * 8;
    const int c0 = w * 2, c1 = w * 2 + 1;
    const long long gA0 = (m0 + c0 * 16 + rsub) * (long long)K + colk;
    const long long gA1 = (m0 + c1 * 16 + rsub) * (long long)K + colk;
    const long long gB0 = (n0 + c0 * 16 + rsub) * (long long)K + colk;
    const long long gB1 = (n0 + c1 * 16 + rsub) * (long long)K + colk;

    const int lA7   = l16 >> 1;
    const int slotE = ((((l16 & 1) * 4 + quad) ^ lA7) * 16) >> 1;
    const int baseAe = (wm * 64 + lA7) * 64 + slotE;
    const int baseBe = (wn * 32 + lA7) * 64 + slotE;

    f32x4 acc[8][4] = {};

    auto stg = [&](int bufi, int tile) {
        const long long kk = (long long)tile * 32;
        bf16* sb = &S[bufi][0];
        glds16(A + gA0 + kk, sb + c0 * 512);
        glds16(A + gA1 + kk, sb + c1 * 512);
        glds16(B + gB0 + kk, sb + 8192 + c0 * 512);
        glds16(B + gB1 + kk, sb + 8192 + c1 * 512);
    };
    auto compute = [&](int tt) {
        const bf16* pA = &S[tt & 3][baseAe];
        const bf16* pB = &S[tt & 3][8192 + baseBe];
        bf16x8 af[8], bfr[4];
#pragma unroll
        for (int m = 0; m < 8; ++m) af[m] = *(const bf16x8*)(pA + m * 512);
#pragma unroll
        for (int n = 0; n < 4; ++n) bfr[n] = *(const bf16x8*)(pB + n * 512);
        __builtin_amdgcn_s_setprio(1);
#pragma unroll
        for (int m = 0; m < 8; ++m)
#pragma unroll
            for (int n = 0; n < 4; ++n)
                acc[m][n] = MFMA16(af[m], bfr[n], acc[m][n]);
        __builtin_amdgcn_s_setprio(0);
    };

    const int nt = K >> 5;

    stg(0, 0); stg(1, 1); stg(2, 2);
    asm volatile("s_waitcnt vmcnt(8)" ::: "memory");
    asm volatile("s_barrier" ::: "memory");

    for (int tt = 0; tt + 3 < nt; ++tt) {
        stg((tt + 3) & 3, tt + 3);
        compute(tt);
        asm volatile("s_waitcnt vmcnt(8)" ::: "memory");
        asm volatile("s_barrier" ::: "memory");
    }
    compute(nt - 3);
    asm volatile("s_waitcnt vmcnt(4)" ::: "memory");
    asm volatile("s_barrier" ::: "memory");
    compute(nt - 2);
    asm volatile("s_waitcnt vmcnt(0)" ::: "memory");
    asm volatile("s_barrier" ::: "memory");
    compute(nt - 1);

    float bs[4];
#pragma unroll
    for (int n = 0; n < 4; ++n) bs[n] = bias[n0 + wn * 64 + n * 16 + l16];

#pragma unroll
    for (int m = 0; m < 8; ++m) {
        const long long mbase = m0 + wm * 128 + m * 16 + quad * 4;
#pragma unroll
        for (int n = 0; n < 4; ++n) {
            const long long nn = n0 + wn * 64 + n * 16 + l16;
            if (MODE == 1) {
                float* Cf = (float*)Cv;
#pragma unroll
                for (int r = 0; r < 4; ++r)
                    Cf[(mbase + r) * N + nn] = acc[m][n][r] + bs[n];
            } else {  // MODE 4: Qs [b][h][1024][128] bf16, scaled
                bf16* Cq = (bf16*)Cv;
                const int h = (int)(nn >> 7), d = (int)(nn & 127);
#pragma unroll
                for (int r = 0; r < 4; ++r) {
                    const long long mr = mbase + r;
                    const long long bb = mr >> 10, s = mr & 1023;
                    Cq[((bb * 32 + h) * 1024 + s) * 128 + d] = (bf16)((acc[m][n][r] + bs[n]) * scale);
                }
            }
        }
    }
}

// ---------- flash attention (4-wave blocks, speculative softmax, post-PV rescale) ----------
// grid 1024 x 256 threads; block = 128 q-rows of one (b,h); 2 blocks/CU.
// Speculative: p = exp2(s - mi_old) computed WITHOUT this tile's max (defer-max);
// after PV, if any row's pmax > 256 (= mx > mi+8), rescale Ot/li by 1/pmax and mi += log2(pmax).
// This breaks the QKT->max->exp serial chain: softmax(s0) overlaps QKT(s1), softmax(s1) overlaps PV(s0).
__global__ __launch_bounds__(256, 2) void attn_k(const bf16* __restrict__ Qs,
                                                 const bf16* __restrict__ Kc,
                                                 const bf16* __restrict__ Vt,
                                                 const int* __restrict__ amask,
                                                 bf16* __restrict__ AO) {
    const int phys = blockIdx.x;
    const int lid = (phys & 7) * 128 + (phys >> 3);   // bijective XCD swizzle (1024 % 8 == 0)
    const int qt = lid & 7, h = (lid >> 3) & 31, b = lid >> 8;
    const int hk = h >> 2;
    const int t = threadIdx.x, lane = t & 63, w = t >> 6;   // w in 0..3
    const int q32 = lane & 31, half = lane >> 5;

    __shared__ bf16 Ksm[2][64 * 128];   // [kv][d], XOR-swizzled 16B slots: slot ^= row&7
    __shared__ bf16 Vsm[2][128 * 64];   // [d][kv], XOR-swizzled 16B slots: slot ^= row&7
    __shared__ unsigned long long Msm[32];

    const bf16* kg = Kc + (long long)(b * 8 + hk) * 2048 * 128;
    const bf16* vg = Vt + (long long)(b * 8 + hk) * 128 * 2048;

    // pack attention mask: word tt covers kv = tt*64 + bit (bit=1 -> masked)
    {
        const int* am = amask + b * 2048;
#pragma unroll
        for (int j = 0; j < 8; ++j) {
            unsigned long long bm = __ballot(am[(w * 8 + j) * 64 + lane] != 0);
            if (lane == 0) Msm[w * 8 + j] = bm;
        }
    }

    bf16x8 qf[8];
    {
        const bf16* qb = Qs + ((long long)(b * 32 + h) * 1024 + qt * 128 + w * 32 + q32) * 128 + half * 8;
#pragma unroll
        for (int kw = 0; kw < 8; ++kw) qf[kw] = *(const bf16x8*)(qb + kw * 16);
    }

    f32x16 Ot[4] = {};
    float mi = 0.f, li = 0.f;   // mi=0 init is safe: |scores| << 127 here; masked p zeroed explicitly

    const int krow = lane >> 4, kslot = lane & 15;   // K: 4 rows x 16 slots (16B) per glds
    const int vrow = lane >> 3, vslot = lane & 7;    // V: 8 rows x 8 slots (16B) per glds

#define STAGE(BUF, KV0) do {                                                                  \
        _Pragma("unroll")                                                                     \
        for (int i = 0; i < 4; ++i) {                                                         \
            const int kr = w * 16 + i * 4 + krow;                                             \
            glds16(kg + (long long)((KV0) + kr) * 128 + ((kslot ^ (kr & 7)) * 8),             \
                   &Ksm[BUF][(w * 16 + i * 4) * 128]);                                        \
        }                                                                                     \
        _Pragma("unroll")                                                                     \
        for (int i = 0; i < 4; ++i) {                                                         \
            const int vd = w * 32 + i * 8 + vrow;                                             \
            glds16(vg + (long long)vd * 2048 + (KV0) + ((vslot ^ (vrow & 7)) * 8),            \
                   &Vsm[BUF][(w * 32 + i * 8) * 64]);                                         \
        }                                                                                     \
    } while (0)

    STAGE(0, 0);
    __syncthreads();

    int buf = 0;
    for (int tt = 0; tt < 32; ++tt) {
        if (tt < 31) STAGE(buf ^ 1, (tt + 1) * 64);
        const unsigned long long mw = Msm[tt];

        // ---- QK^T, two independent accumulator chains ----
        f32x16 s0 = {}, s1 = {};
        __builtin_amdgcn_s_setprio(1);
#pragma unroll
        for (int kw = 0; kw < 8; ++kw) {
            const int sl = ((kw * 2 + half) ^ (q32 & 7)) * 8;
            bf16x8 k0 = *(const bf16x8*)(&Ksm[buf][q32 * 128 + sl]);
            s0 = MFMA32(k0, qf[kw], s0);
        }
#pragma unroll
        for (int kw = 0; kw < 8; ++kw) {
            const int sl = ((kw * 2 + half) ^ (q32 & 7)) * 8;
            bf16x8 k1 = *(const bf16x8*)(&Ksm[buf][(32 + q32) * 128 + sl]);
            s1 = MFMA32(k1, qf[kw], s1);
        }
        __builtin_amdgcn_s_setprio(0);

        float a0 = 0.f, a1 = 0.f, a2 = 0.f, a3 = 0.f;   // sum chains
        float p0 = 0.f, p1 = 0.f, p2 = 0.f, p3 = 0.f;   // pmax chains
        bf16x8 pf[4];

        // ---- softmax s0 (speculative; overlaps the s1 MFMA chain above) ----
#pragma unroll
        for (int i = 0; i < 16; ++i) s0[i] = exp2f(s0[i] - mi);
        if (mw) {
#pragma unroll
            for (int g = 0; g < 4; ++g)
#pragma unroll
                for (int j = 0; j < 4; ++j)
                    if ((mw >> (j + 8 * g + 4 * half)) & 1) s0[g * 4 + j] = 0.f;
        }
#pragma unroll
        for (int i = 0; i < 16; i += 4) {
            a0 += s0[i + 0]; p0 = fmaxf(p0, s0[i + 0]);
            a1 += s0[i + 1]; p1 = fmaxf(p1, s0[i + 1]);
            a2 += s0[i + 2]; p2 = fmaxf(p2, s0[i + 2]);
            a3 += s0[i + 3]; p3 = fmaxf(p3, s0[i + 3]);
        }
#pragma unroll
        for (int wp = 0; wp < 2; ++wp) {
            unsigned xa = cvtpk_bf16(s0[8 * wp + 0], s0[8 * wp + 1]);
            unsigned xb = cvtpk_bf16(s0[8 * wp + 2], s0[8 * wp + 3]);
            unsigned ya = cvtpk_bf16(s0[8 * wp + 4], s0[8 * wp + 5]);
            unsigned yb = cvtpk_bf16(s0[8 * wp + 6], s0[8 * wp + 7]);
            auto rA = __builtin_amdgcn_permlane32_swap(xa, ya, false, false);
            auto rB = __builtin_amdgcn_permlane32_swap(xb, yb, false, false);
            u32x4v fw;
            fw[0] = (unsigned)rA[0]; fw[1] = (unsigned)rB[0];
            fw[2] = (unsigned)rA[1]; fw[3] = (unsigned)rB[1];
            pf[wp] = __builtin_bit_cast(bf16x8, fw);
        }

        // ---- PV for kv 0..31 (overlaps softmax s1 below) ----
        __builtin_amdgcn_s_setprio(1);
#pragma unroll
        for (int kvw = 0; kvw < 2; ++kvw) {
            const int sl = ((kvw * 2 + half) ^ (q32 & 7)) * 8;
#pragma unroll
            for (int dt = 0; dt < 4; ++dt) {
                bf16x8 vf = *(const bf16x8*)(&Vsm[buf][(dt * 32 + q32) * 64 + sl]);
                Ot[dt] = MFMA32(vf, pf[kvw], Ot[dt]);
            }
        }
        __builtin_amdgcn_s_setprio(0);

        // ---- softmax s1 ----
#pragma unroll
        for (int i = 0; i < 16; ++i) s1[i] = exp2f(s1[i] - mi);
        if (mw) {
#pragma unroll
            for (int g = 0; g < 4; ++g)
#pragma unroll
                for (int j = 0; j < 4; ++j)
                    if ((mw >> (32 + j + 8 * g + 4 * half)) & 1) s1[g * 4 + j] = 0.f;
        }
#pragma unroll
        for (int i = 0; i < 16; i += 4) {
            a0 += s1[i + 0]; p0 = fmaxf(p0, s1[i + 0]);
            a1 += s1[i + 1]; p1 = fmaxf(p1, s1[i + 1]);
            a2 += s1[i + 2]; p2 = fmaxf(p2, s1[i + 2]);
            a3 += s1[i + 3]; p3 = fmaxf(p3, s1[i + 3]);
        }
#pragma unroll
        for (int wp = 0; wp < 2; ++wp) {
            unsigned xa = cvtpk_bf16(s1[8 * wp + 0], s1[8 * wp + 1]);
            unsigned xb = cvtpk_bf16(s1[8 * wp + 2], s1[8 * wp + 3]);
            unsigned ya = cvtpk_bf16(s1[8 * wp + 4], s1[8 * wp + 5]);
            unsigned yb = cvtpk_bf16(s1[8 * wp + 6], s1[8 * wp + 7]);
            auto rA = __builtin_amdgcn_permlane32_swap(xa, ya, false, false);
            auto rB = __builtin_amdgcn_permlane32_swap(xb, yb, false, false);
            u32x4v fw;
            fw[0] = (unsigned)rA[0]; fw[1] = (unsigned)rB[0];
            fw[2] = (unsigned)rA[1]; fw[3] = (unsigned)rB[1];
            pf[2 + wp] = __builtin_bit_cast(bf16x8, fw);
        }

        // ---- PV for kv 32..63 ----
        __builtin_amdgcn_s_setprio(1);
#pragma unroll
        for (int kvw = 2; kvw < 4; ++kvw) {
            const int sl = ((kvw * 2 + half) ^ (q32 & 7)) * 8;
#pragma unroll
            for (int dt = 0; dt < 4; ++dt) {
                bf16x8 vf = *(const bf16x8*)(&Vsm[buf][(dt * 32 + q32) * 64 + sl]);
                Ot[dt] = MFMA32(vf, pf[kvw], Ot[dt]);
            }
        }
        __builtin_amdgcn_s_setprio(0);

        // ---- finish: row sum, row pmax, deferred rescale (exact post-hoc correction) ----
        float sum = (a0 + a1) + (a2 + a3);
        {
            auto r = __builtin_amdgcn_permlane32_swap(__builtin_bit_cast(unsigned, sum),
                                                      __builtin_bit_cast(unsigned, sum), false, false);
            sum += __builtin_bit_cast(float, (unsigned)(half ? r[0] : r[1]));
        }
        li += sum;
        float pm = fmaxf(fmaxf(p0, p1), fmaxf(p2, p3));
        {
            auto r = __builtin_amdgcn_permlane32_swap(__builtin_bit_cast(unsigned, pm),
                                                      __builtin_bit_cast(unsigned, pm), false, false);
            pm = fmaxf(pm, fmaxf(__builtin_bit_cast(float, (unsigned)r[0]),
                                 __builtin_bit_cast(float, (unsigned)r[1])));
        }
        if (__any(pm > 256.f)) {
            const float al  = pm > 1.f ? 1.f / pm : 1.f;       // never amplify
            const float dmi = pm > 1.f ? log2f(pm) : 0.f;
            mi += dmi;
            li *= al;
#pragma unroll
            for (int dt = 0; dt < 4; ++dt)
#pragma unroll
                for (int i = 0; i < 16; ++i) Ot[dt][i] *= al;
        }

        __syncthreads();
        buf ^= 1;
    }
#undef STAGE

    const float inv = 1.f / li;
    const long long token = (long long)b * 1024 + qt * 128 + w * 32 + q32;
    bf16* ao = AO + token * 4096 + h * 128 + half * 4;
#pragma unroll
    for (int dt = 0; dt < 4; ++dt)
#pragma unroll
        for (int g = 0; g < 4; ++g) {
            u16x4v pk;
#pragma unroll
            for (int j = 0; j < 4; ++j)
                pk[j] = __builtin_bit_cast(unsigned short, (bf16)(Ot[dt][g * 4 + j] * inv));
            *(u16x4v*)(ao + dt * 32 + g * 8) = pk;
        }
}

// ---------- host launch ----------
extern "C" void kernel_launch(void* const* d_in, const int* in_sizes, int n_in,
                              void* d_out, int out_size, void* d_ws, size_t ws_size,
                              hipStream_t stream) {
    const float* hidden = (const float*)d_in[0];
    const float* past_k = (const float*)d_in[1];
    const float* past_v = (const float*)d_in[2];
    const int*   amask  = (const int*)d_in[3];
    const float* Wq = (const float*)d_in[4];
    const float* bq = (const float*)d_in[5];
    const float* Wk = (const float*)d_in[6];
    const float* bk = (const float*)d_in[7];
    const float* Wv = (const float*)d_in[8];
    const float* bv = (const float*)d_in[9];
    const float* Wo = (const float*)d_in[10];
    const float* bo = (const float*)d_in[11];

    // workspace layout (128 MB total)
    char* ws = (char*)d_ws;
    bf16* Xb   = (bf16*)(ws);                             // 32MB  hidden bf16 [4096][4096]
    bf16* Wqb  = (bf16*)(ws + (1ll << 25));               // 32MB  Wq bf16, later reused for Wo
    bf16* Wkvb = (bf16*)(ws + (1ll << 26));               // 16MB  [Wk;Wv] bf16 [2048][4096]
    bf16* AOb  = (bf16*)(ws + (1ll << 26) + (1ll << 24)); // 32MB @80MB: attention out bf16
    // scratch inside d_out (64MB, dead before final GEMM writes it)
    char* oc = (char*)d_out;
    bf16* Qb  = (bf16*)(oc);                              // 32MB: scaled Q bf16 [4][32][1024][128]
    bf16* Kb  = (bf16*)(oc + (1ll << 25));                // 16MB: K cache [4][8][2048][128]
    bf16* Vtb = (bf16*)(oc + (1ll << 25) + (1ll << 24));  // 16MB: V^T cache [4][8][128][2048]

    const float qscale = 0.08838834764831845f * 1.44269504088896340f; // 1/sqrt(128) * log2(e)

    fused_cvt_k<<<22528, 256, 0, stream>>>(hidden, Wq, Wk, Wv, past_k, Xb, Wqb, Wkvb, Kb);
    cvt_pastv_k<<<512, 256, 0, stream>>>(past_v, Vtb);

    gemm256<4><<<dim3(16, 16), 512, 0, stream>>>(Xb, Wqb, bq, (void*)Qb, 4096, 4096, 4096, qscale);
    gemm_kv<<<dim3(16, 32), 256, 0, stream>>>(Xb, Wkvb, bk, bv, Kb, Vtb, 4096);

    // Wo -> bf16 (reuse Wqb buffer; stream-ordered after Q projection consumed it)
    cvt_bf16_k<<<8192, 256, 0, stream>>>(Wo, Wqb, 16777216ll);

    attn_k<<<1024, 256, 0, stream>>>(Qb, Kb, Vtb, amask, AOb);

    gemm256<1><<<dim3(16, 16), 512, 0, stream>>>(AOb, Wqb, bo, d_out, 4096, 4096, 4096, 1.0f);
}